// Round 13
// baseline (1396.904 us; speedup 1.0000x reference)
//
#include <hip/hip_runtime.h>
#include <hip/hip_bf16.h>
#include <math.h>

#define N_NODES 50000
#define N_EDGES 800000
#define D_NODE 64
#define D_EDGE 32
#define OUT_DIM 32
#define NUM_HEADS 4
#define NCH 49            // ceil(N_NODES/1024)

// ---- bf16 helpers (manual RNE pack, shift unpack) ----
__device__ __forceinline__ unsigned bf16rne(float x) {
    unsigned u = __float_as_uint(x);
    unsigned r = ((u >> 16) & 1u) + 0x7fffu;
    return (u + r) >> 16;
}
__device__ __forceinline__ float2 unpack_bf2(unsigned p) {
    return make_float2(__uint_as_float(p << 16), __uint_as_float(p & 0xffff0000u));
}

// ---- K0: detect attn_mask storage dtype (u8 / f32 / i32) ----
__global__ void k_detect(const unsigned char* __restrict__ mask, int* __restrict__ mode) {
    __shared__ int cnt;
    if (threadIdx.x == 0) cnt = 0;
    __syncthreads();
    int c = 0;
    for (int i = threadIdx.x; i < 4096; i += 256) c += (mask[i] != 0);
    atomicAdd(&cnt, c);
    __syncthreads();
    if (threadIdx.x == 0) {
        int md;
        if (cnt > (4096 * 70) / 100)      md = 0;  // uint8 bool
        else if (cnt > (4096 * 35) / 100) md = 1;  // float32
        else                              md = 2;  // int32
        *mode = md;
    }
}

__device__ __forceinline__ bool loadmask(const void* m, int mode, int e) {
    if (mode == 0) return ((const unsigned char*)m)[e] != 0;
    if (mode == 1) return ((const float*)m)[e] != 0.f;
    return ((const int*)m)[e] != 0;
}

// ---- K1: node precompute GEMM ----
// mb=0: Psrc (fp32) = nf @ Wa[0:64]
// mb=1: PT2[n][l].x (bf16x2) = (nf @ Wa[96:160]) dims 2l,2l+1   (tgt block of W_a)
// mb=2: PT2[n][l].y (bf16x2) = (nf @ Wm[32:96])  dims 2l,2l+1   (tgt block of W_m)
__global__ __launch_bounds__(256) void k_nodegemm(
    const float* __restrict__ nf, const float* __restrict__ Wa, const float* __restrict__ Wm,
    float* __restrict__ Psrc, unsigned* __restrict__ PT2) {
    __shared__ float At[64][72];
    __shared__ float Bt[64][128];
    const int mb = blockIdx.y;
    const float* Wsrc = (mb == 0) ? Wa : (mb == 1 ? (Wa + 96 * 128) : (Wm + 32 * 128));
    const int n0 = blockIdx.x * 64;
    const int tid = threadIdx.x;

    for (int i = tid; i < 1024; i += 256) {
        int r = i >> 4;
        int kc = (i & 15) << 2;
        float4 v = make_float4(0.f, 0.f, 0.f, 0.f);
        if (n0 + r < N_NODES) v = *(const float4*)(nf + (size_t)(n0 + r) * 64 + kc);
        At[kc + 0][r] = v.x; At[kc + 1][r] = v.y; At[kc + 2][r] = v.z; At[kc + 3][r] = v.w;
    }
    for (int i = tid; i < 2048; i += 256) {
        int k = i >> 5;
        int c = (i & 31) << 2;
        *(float4*)(&Bt[k][c]) = *(const float4*)(Wsrc + (size_t)k * 128 + c);
    }
    __syncthreads();

    const int ty = tid >> 5;
    const int tx = tid & 31;
    float acc[8][4];
#pragma unroll
    for (int r = 0; r < 8; r++)
#pragma unroll
        for (int c = 0; c < 4; c++) acc[r][c] = 0.f;

    for (int k = 0; k < 64; k++) {
        float4 b = *(const float4*)(&Bt[k][tx * 4]);
        float4 a0 = *(const float4*)(&At[k][ty * 8]);
        float4 a1 = *(const float4*)(&At[k][ty * 8 + 4]);
        float a[8] = {a0.x, a0.y, a0.z, a0.w, a1.x, a1.y, a1.z, a1.w};
#pragma unroll
        for (int r = 0; r < 8; r++) {
            acc[r][0] += a[r] * b.x; acc[r][1] += a[r] * b.y;
            acc[r][2] += a[r] * b.z; acc[r][3] += a[r] * b.w;
        }
    }
    for (int r = 0; r < 8; r++) {
        int n = n0 + ty * 8 + r;
        if (n >= N_NODES) continue;
        if (mb == 0) {
            *(float4*)(Psrc + (size_t)n * 128 + tx * 4) =
                make_float4(acc[r][0], acc[r][1], acc[r][2], acc[r][3]);
        } else {
            unsigned p0 = bf16rne(acc[r][0]) | (bf16rne(acc[r][1]) << 16);
            unsigned p1 = bf16rne(acc[r][2]) | (bf16rne(acc[r][3]) << 16);
            unsigned fld = (mb == 1) ? 0u : 1u;   // .x for Ptgta, .y for Ptgtm
            PT2[((size_t)n * 64 + 2 * tx) * 2 + fld] = p0;
            PT2[((size_t)n * 64 + 2 * tx + 1) * 2 + fld] = p1;
        }
    }
}

// ---- K2: degree count ----
__global__ void k_deg(const int* __restrict__ src, int* __restrict__ deg) {
    int i = blockIdx.x * blockDim.x + threadIdx.x;
    if (i < N_EDGES) atomicAdd(&deg[src[i]], 1);
}

// ---- K3a: per-1024-chunk sums ----
__global__ void k_scan_partial(const int* __restrict__ deg, int* __restrict__ csum) {
    __shared__ int sd[256];
    int b = blockIdx.x, tid = threadIdx.x;
    int s = 0, st = b * 1024;
    for (int i = tid; i < 1024; i += 256) {
        int idx = st + i;
        if (idx < N_NODES) s += deg[idx];
    }
    sd[tid] = s; __syncthreads();
    for (int off = 128; off > 0; off >>= 1) {
        if (tid < off) sd[tid] += sd[tid + off];
        __syncthreads();
    }
    if (tid == 0) csum[b] = sd[0];
}

// ---- K3b: exclusive scan of chunk sums ----
__global__ void k_scan_chunks(int* __restrict__ csum) {
    if (threadIdx.x == 0 && blockIdx.x == 0) {
        int acc = 0;
        for (int i = 0; i < NCH; i++) { int v = csum[i]; csum[i] = acc; acc += v; }
    }
}

// ---- K3c: in-chunk scan -> base offsets ----
__global__ __launch_bounds__(1024) void k_scan_apply(
    const int* __restrict__ deg, const int* __restrict__ csum, int* __restrict__ basep) {
    __shared__ int sd[1024];
    int b = blockIdx.x, tid = threadIdx.x;
    int idx = b * 1024 + tid;
    int v = (idx < N_NODES) ? deg[idx] : 0;
    sd[tid] = v; __syncthreads();
    for (int off = 1; off < 1024; off <<= 1) {
        int add = (tid >= off) ? sd[tid - off] : 0;
        __syncthreads();
        sd[tid] += add;
        __syncthreads();
    }
    if (idx < N_NODES) basep[idx] = csum[b] + sd[tid] - v;
}

// ---- K4: scatter edges into per-node buckets, building tmE directly ----
// tmE[p] = (e<<32) | (mask<<16) | tgt   (tgt < 50000 < 65536, fits 16 bits)
__global__ void k_scatter(const int* __restrict__ src, const int* __restrict__ tgt,
                          const void* __restrict__ mask, const int* __restrict__ modep,
                          const int* __restrict__ basep, int* __restrict__ cursor,
                          unsigned long long* __restrict__ tmE) {
    int i = blockIdx.x * blockDim.x + threadIdx.x;
    if (i < N_EDGES) {
        const int mode = *modep;
        int s = src[i];
        int p = basep[s] + atomicAdd(&cursor[s], 1);
        unsigned long long mk = loadmask(mask, mode, i) ? 1ull : 0ull;
        tmE[p] = ((unsigned long long)(unsigned)i << 32) | (mk << 16)
               | (unsigned long long)(unsigned)tgt[i];
    }
}

// ---- K5: fused per-node GATv2, 2 nodes (2 independent edge streams) per wave ----
// Lane l: dims (2l, 2l+1). Doubled MLP: two PT2/ef/tmE prefetch chains in flight.
// No max pass: u = exp(min(logit,60)); masked -> 0; dead node <=> den==0 -> uniform fallback.
// Message GEMM factored out per node: sum_e u*(ef@Wm) == (sum_e u*ef)@Wm.
__global__ __launch_bounds__(256, 3) void k_fused(
    const float* __restrict__ ef, const unsigned long long* __restrict__ tmE,
    const float* __restrict__ Wa, const float* __restrict__ Wm, const float* __restrict__ aw,
    const float* __restrict__ Psrc, const uint2* __restrict__ PT2,
    const int* __restrict__ deg, const int* __restrict__ basep,
    float* __restrict__ out) {
    const int lane = threadIdx.x & 63;
    const int wv = threadIdx.x >> 6;
    const int wid = blockIdx.x * 4 + wv;        // 0..24999 (grid 6250 exact)
    const int nA = wid * 2, nB = nA + 1;
    const int l15 = lane & 15;
    const int base16 = lane & 48;
    const int d0 = lane * 2;

    // W_a edge-block columns (d0,d0+1) in VGPRs — shared by both streams
    float2 W[32];
#pragma unroll
    for (int j = 0; j < 32; j++)
        W[j] = *(const float2*)(Wa + (size_t)(64 + j) * 128 + d0);

    const float2 awv = *(const float2*)(aw + 2 * l15);
    const int dgA = deg[nA], bsA = basep[nA];
    const int dgB = deg[nB], bsB = basep[nB];
    const float2 psA = *(const float2*)(Psrc + (size_t)nA * 128 + d0);
    const float2 psB = *(const float2*)(Psrc + (size_t)nB * 128 + d0);

    float accA0 = 0.f, accA1 = 0.f, wA0 = 0.f, wA1 = 0.f, denA = 0.f;
    float acUA0 = 0.f, acUA1 = 0.f, wUA0 = 0.f, wUA1 = 0.f;
    float accB0 = 0.f, accB1 = 0.f, wB0 = 0.f, wB1 = 0.f, denB = 0.f;
    float acUB0 = 0.f, acUB1 = 0.f, wUB0 = 0.f, wUB1 = 0.f;

    const int last = N_EDGES - 1;
    // pipeline preload per stream: tmE i=0..2; PT i=0,1; ef i=0
    unsigned long long tmA0 = tmE[min(bsA + 0, last)];
    unsigned long long tmA1 = tmE[min(bsA + 1, last)];
    unsigned long long tmA2 = tmE[min(bsA + 2, last)];
    unsigned long long tmB0 = tmE[min(bsB + 0, last)];
    unsigned long long tmB1 = tmE[min(bsB + 1, last)];
    unsigned long long tmB2 = tmE[min(bsB + 2, last)];
    uint2 ptA0 = PT2[(size_t)(tmA0 & 0xFFFFu) * 64 + lane];
    uint2 ptA1 = PT2[(size_t)(tmA1 & 0xFFFFu) * 64 + lane];
    uint2 ptB0 = PT2[(size_t)(tmB0 & 0xFFFFu) * 64 + lane];
    uint2 ptB1 = PT2[(size_t)(tmB1 & 0xFFFFu) * 64 + lane];
    float2 efA0 = *(const float2*)(ef + (size_t)(tmA0 >> 32) * 32 + 2 * l15);
    float2 efB0 = *(const float2*)(ef + (size_t)(tmB0 >> 32) * 32 + 2 * l15);

    const int mx = max(dgA, dgB);
    for (int i = 0; i < mx; i++) {
        // issue next-stage loads (both streams)
        unsigned long long tmA3 = tmE[min(bsA + i + 3, last)];
        unsigned long long tmB3 = tmE[min(bsB + i + 3, last)];
        uint2 ptA2 = PT2[(size_t)(tmA2 & 0xFFFFu) * 64 + lane];
        uint2 ptB2 = PT2[(size_t)(tmB2 & 0xFFFFu) * 64 + lane];
        float2 efA1 = *(const float2*)(ef + (size_t)(tmA1 >> 32) * 32 + 2 * l15);
        float2 efB1 = *(const float2*)(ef + (size_t)(tmB1 >> 32) * 32 + 2 * l15);

        // compute both edges (interleaved for ILP)
        float2 pafA = unpack_bf2(ptA0.x);
        float2 pafB = unpack_bf2(ptB0.x);
        float aA0 = psA.x + pafA.x, aA1 = psA.y + pafA.y;
        float aB0 = psB.x + pafB.x, aB1 = psB.y + pafB.y;
#pragma unroll
        for (int j = 0; j < 32; j += 2) {
            int sl = base16 + (j >> 1);
            float exA = __shfl(efA0.x, sl);
            float eyA = __shfl(efA0.y, sl);
            float exB = __shfl(efB0.x, sl);
            float eyB = __shfl(efB0.y, sl);
            aA0 += exA * W[j].x + eyA * W[j + 1].x;
            aA1 += exA * W[j].y + eyA * W[j + 1].y;
            aB0 += exB * W[j].x + eyB * W[j + 1].x;
            aB1 += exB * W[j].y + eyB * W[j + 1].y;
        }
        float lrA0 = (aA0 >= 0.f) ? aA0 : 0.2f * aA0;
        float lrA1 = (aA1 >= 0.f) ? aA1 : 0.2f * aA1;
        float lrB0 = (aB0 >= 0.f) ? aB0 : 0.2f * aB0;
        float lrB1 = (aB1 >= 0.f) ? aB1 : 0.2f * aB1;
        float vA = lrA0 * awv.x + lrA1 * awv.y;
        float vB = lrB0 * awv.x + lrB1 * awv.y;
#pragma unroll
        for (int off = 8; off > 0; off >>= 1) {
            vA += __shfl_xor(vA, off);
            vB += __shfl_xor(vB, off);
        }
        if (i < dgA) {                      // wave-uniform branch
            float u = ((tmA0 >> 16) & 1ull) ? __expf(fminf(vA, 60.f)) : 0.f;
            float2 pmf = unpack_bf2(ptA0.y);
            accA0 += u * pmf.x; accA1 += u * pmf.y;
            wA0 += u * efA0.x;  wA1 += u * efA0.y;
            denA += u;
            acUA0 += pmf.x;     acUA1 += pmf.y;
            wUA0 += efA0.x;     wUA1 += efA0.y;
        }
        if (i < dgB) {
            float u = ((tmB0 >> 16) & 1ull) ? __expf(fminf(vB, 60.f)) : 0.f;
            float2 pmf = unpack_bf2(ptB0.y);
            accB0 += u * pmf.x; accB1 += u * pmf.y;
            wB0 += u * efB0.x;  wB1 += u * efB0.y;
            denB += u;
            acUB0 += pmf.x;     acUB1 += pmf.y;
            wUB0 += efB0.x;     wUB1 += efB0.y;
        }

        // rotate rings
        tmA0 = tmA1; tmA1 = tmA2; tmA2 = tmA3;
        tmB0 = tmB1; tmB1 = tmB2; tmB2 = tmB3;
        ptA0 = ptA1; ptA1 = ptA2;
        ptB0 = ptB1; ptB1 = ptB2;
        efA0 = efA1; efB0 = efB1;
    }

    // dead-node fallback + per-node tail GEMM, stream A then B
    {
        bool dead = (dgA > 0) && (denA == 0.f);
        float sw0 = dead ? wUA0 : wA0, sw1 = dead ? wUA1 : wA1;
        float sa0 = dead ? acUA0 : accA0, sa1 = dead ? acUA1 : accA1;
        float sden = dead ? (float)dgA : denA;
        float t0 = 0.f, t1 = 0.f;
#pragma unroll
        for (int k = 0; k < 32; k += 2) {
            int sl = base16 + (k >> 1);
            float wa = __shfl(sw0, sl);
            float wb = __shfl(sw1, sl);
            float2 m0 = *(const float2*)(Wm + (size_t)k * 128 + d0);
            float2 m1 = *(const float2*)(Wm + (size_t)(k + 1) * 128 + d0);
            t0 += wa * m0.x + wb * m1.x;
            t1 += wa * m0.y + wb * m1.y;
        }
        float o0 = (dgA > 0) ? (sa0 + t0) / sden : 0.f;
        float o1 = (dgA > 0) ? (sa1 + t1) / sden : 0.f;
        *(float2*)(out + (size_t)nA * 128 + d0) = make_float2(o0, o1);
    }
    {
        bool dead = (dgB > 0) && (denB == 0.f);
        float sw0 = dead ? wUB0 : wB0, sw1 = dead ? wUB1 : wB1;
        float sa0 = dead ? acUB0 : accB0, sa1 = dead ? acUB1 : accB1;
        float sden = dead ? (float)dgB : denB;
        float t0 = 0.f, t1 = 0.f;
#pragma unroll
        for (int k = 0; k < 32; k += 2) {
            int sl = base16 + (k >> 1);
            float wa = __shfl(sw0, sl);
            float wb = __shfl(sw1, sl);
            float2 m0 = *(const float2*)(Wm + (size_t)k * 128 + d0);
            float2 m1 = *(const float2*)(Wm + (size_t)(k + 1) * 128 + d0);
            t0 += wa * m0.x + wb * m1.x;
            t1 += wa * m0.y + wb * m1.y;
        }
        float o0 = (dgB > 0) ? (sa0 + t0) / sden : 0.f;
        float o1 = (dgB > 0) ? (sa1 + t1) / sden : 0.f;
        *(float2*)(out + (size_t)nB * 128 + d0) = make_float2(o0, o1);
    }
}

extern "C" void kernel_launch(void* const* d_in, const int* in_sizes, int n_in,
                              void* d_out, int out_size, void* d_ws, size_t ws_size,
                              hipStream_t stream) {
    const float* nf = (const float*)d_in[0];
    const float* ef = (const float*)d_in[1];
    const int* eidx = (const int*)d_in[2];
    const void* mask = d_in[3];
    const float* Wa = (const float*)d_in[4];
    const float* Wm = (const float*)d_in[5];
    const float* aw = (const float*)d_in[6];
    const int* src = eidx;
    const int* tgt = eidx + N_EDGES;
    float* out = (float*)d_out;

    char* ws = (char*)d_ws;
    size_t off = 0;
    auto alloc = [&](size_t bytes) -> void* {
        void* p = ws + off;
        off += (bytes + 255) & ~(size_t)255;
        return p;
    };
    int* mode       = (int*)alloc(256);
    float* Psrc     = (float*)alloc((size_t)N_NODES * 128 * 4);
    unsigned* PT2   = (unsigned*)alloc((size_t)N_NODES * 64 * 8);   // [N][64] uint2
    int* deg        = (int*)alloc((size_t)N_NODES * 4);
    int* cursor     = (int*)alloc((size_t)N_NODES * 4);
    int* basep      = (int*)alloc((size_t)N_NODES * 4);
    int* csum       = (int*)alloc((size_t)NCH * 4);
    unsigned long long* tmE = (unsigned long long*)alloc((size_t)N_EDGES * 8);

    hipMemsetAsync(deg, 0, (size_t)N_NODES * 4, stream);
    hipMemsetAsync(cursor, 0, (size_t)N_NODES * 4, stream);

    k_detect<<<1, 256, 0, stream>>>((const unsigned char*)mask, mode);
    k_nodegemm<<<dim3((N_NODES + 63) / 64, 3), 256, 0, stream>>>(nf, Wa, Wm, Psrc, PT2);
    k_deg<<<(N_EDGES + 255) / 256, 256, 0, stream>>>(src, deg);
    k_scan_partial<<<NCH, 256, 0, stream>>>(deg, csum);
    k_scan_chunks<<<1, 64, 0, stream>>>(csum);
    k_scan_apply<<<NCH, 1024, 0, stream>>>(deg, csum, basep);
    k_scatter<<<(N_EDGES + 255) / 256, 256, 0, stream>>>(src, tgt, mask, mode,
                                                         basep, cursor, tmE);
    k_fused<<<N_NODES / 8, 256, 0, stream>>>(ef, tmE, Wa, Wm, aw,
                                             Psrc, (const uint2*)PT2, deg, basep, out);
}